// Round 9
// baseline (218.787 us; speedup 1.0000x reference)
//
#include <hip/hip_runtime.h>
#include <hip/hip_bf16.h>
#include <stdint.h>

// B=2, S=2048, E=1024, H=16, DK=64, causal. Device buffers f32; internal bf16.

typedef __attribute__((ext_vector_type(4))) float f32x4;
typedef __attribute__((ext_vector_type(8))) __bf16 bf16x8;
typedef unsigned short u16;

#define QSCALE 0.18033688011112042f  // 0.125 * log2(e): folded into Q at GEMM1

__device__ __forceinline__ u16 f2bf(float f) {
  __bf16 h = (__bf16)f;
  union { __bf16 b; u16 u; } c; c.b = h; return c.u;
}

__device__ __forceinline__ void gload_lds16(const u16* g, u16* l) {
  __builtin_amdgcn_global_load_lds((const __attribute__((address_space(1))) void*)g,
                                   (__attribute__((address_space(3))) void*)l, 16, 0, 0);
}

// Fragment read from [rows][64]-bf16 LDS tile, 16B-slot XOR swizzle slot^=(row&7).
__device__ __forceinline__ bf16x8 ld_frag(const u16* ls, int row, int kh, int lane) {
  int sl = ((kh << 2) | (lane >> 4)) ^ (row & 7);
  return *(const bf16x8*)(ls + row * 64 + sl * 8);
}

__device__ __forceinline__ bf16x8 cvt8(f32x4 a, f32x4 b) {
  union { u16 u[8]; bf16x8 v; } o;
#pragma unroll
  for (int j = 0; j < 4; ++j) { o.u[j] = f2bf(a[j]); o.u[4 + j] = f2bf(b[j]); }
  return o.v;
}

// fused f32->bf16 for x, w_in, w_out (8 elems/thread, one launch)
__global__ __launch_bounds__(256) void cvt_all(
    const float* __restrict__ x, const float* __restrict__ wi,
    const float* __restrict__ wo,
    u16* __restrict__ xb, u16* __restrict__ wib, u16* __restrict__ wob,
    int n1, int n2, int n3) {
  int i = blockIdx.x * 256 + threadIdx.x;
  const float* src; u16* dst; int off;
  if (i < n1) { src = x; dst = xb; off = i; }
  else if (i < n1 + n2) { src = wi; dst = wib; off = i - n1; }
  else if (i < n1 + n2 + n3) { src = wo; dst = wob; off = i - n1 - n2; }
  else return;
  const f32x4* p = (const f32x4*)(src + (size_t)off * 8);
  *(bf16x8*)(dst + (size_t)off * 8) = cvt8(p[0], p[1]);
}

// ---------------------------------------------------------------------------
// GEMM-BT: C[M][N] = A[M][K] * Bw[N][K]^T + bias[N]; 128x128 tile, BK=64,
// 4 waves (2x2), dbuf LDS. bf16 ops: global_load_lds w16 (pre-swizzled src).
// f32 ops: reg-stage issue-early/write-late. XCD-remapped 1D grid.
// MODE 0: N=3072 QKV -> Q[bh][s][64] (PRE-SCALED by QSCALE), K[bh][s][64],
//         VT[bh][64][s] (bf16).   MODE 1: N=1024 out-proj -> f32 [M][1024]
// ---------------------------------------------------------------------------
template <int MODE, bool AF32, bool BF32>
__global__ __launch_bounds__(256, 2) void gemm_bt(
    const void* Ap, const void* Bp, const float* __restrict__ bias,
    void* out0, u16* __restrict__ out1, u16* __restrict__ out2, int K, int nbn) {
  __shared__ __align__(16) u16 lsA[2][128 * 64];
  __shared__ __align__(16) u16 lsB[2][128 * 64];
  const float* Af = (const float*)Ap; const u16* Ab = (const u16*)Ap;
  const float* Bf = (const float*)Bp; const u16* Bb = (const u16*)Bp;
  const int tid = threadIdx.x, lane = tid & 63, wid = tid >> 6;
  const int cpx = gridDim.x >> 3;
  const int wg = (blockIdx.x & 7) * cpx + (blockIdx.x >> 3);
  const int bm = wg / nbn, bn = wg % nbn;
  const int rowA0 = bm * 128, rowB0 = bn * 128;
  const int wm = wid >> 1, wn = wid & 1;

  f32x4 ra[4][2], rb[4][2];

  auto issue = [&](int buf, int k0) {
    if constexpr (AF32) {
#pragma unroll
      for (int i = 0; i < 4; ++i) {
        int u = i * 256 + tid, r = u >> 3, s = u & 7;
        const float* p = Af + (size_t)(rowA0 + r) * K + k0 + s * 8;
        ra[i][0] = *(const f32x4*)p; ra[i][1] = *(const f32x4*)(p + 4);
      }
    } else {
#pragma unroll
      for (int i = 0; i < 4; ++i) {
        int u = i * 256 + tid, r = u >> 3, s = u & 7;
        int gk = k0 + ((s ^ (r & 7)) << 3);
        gload_lds16(Ab + (size_t)(rowA0 + r) * K + gk,
                    &lsA[buf][(i * 256 + wid * 64) << 3]);
      }
    }
    if constexpr (BF32) {
#pragma unroll
      for (int i = 0; i < 4; ++i) {
        int u = i * 256 + tid, r = u >> 3, s = u & 7;
        const float* p = Bf + (size_t)(rowB0 + r) * K + k0 + s * 8;
        rb[i][0] = *(const f32x4*)p; rb[i][1] = *(const f32x4*)(p + 4);
      }
    } else {
#pragma unroll
      for (int i = 0; i < 4; ++i) {
        int u = i * 256 + tid, r = u >> 3, s = u & 7;
        int gk = k0 + ((s ^ (r & 7)) << 3);
        gload_lds16(Bb + (size_t)(rowB0 + r) * K + gk,
                    &lsB[buf][(i * 256 + wid * 64) << 3]);
      }
    }
  };
  auto commit = [&](int buf) {
    if constexpr (AF32) {
#pragma unroll
      for (int i = 0; i < 4; ++i) {
        int u = i * 256 + tid, r = u >> 3, s = u & 7;
        *(bf16x8*)&lsA[buf][r * 64 + ((s ^ (r & 7)) << 3)] = cvt8(ra[i][0], ra[i][1]);
      }
    }
    if constexpr (BF32) {
#pragma unroll
      for (int i = 0; i < 4; ++i) {
        int u = i * 256 + tid, r = u >> 3, s = u & 7;
        *(bf16x8*)&lsB[buf][r * 64 + ((s ^ (r & 7)) << 3)] = cvt8(rb[i][0], rb[i][1]);
      }
    }
  };

  f32x4 acc[4][4] = {};
  const int NT = K >> 6;
  issue(0, 0);
  commit(0);
  asm volatile("s_waitcnt vmcnt(0)" ::: "memory");
  __syncthreads();
  int cur = 0;
  for (int t = 0; t < NT; ++t) {
    if (t + 1 < NT) issue(cur ^ 1, (t + 1) << 6);
    const u16* la = lsA[cur];
    const u16* lb = lsB[cur];
    bf16x8 af[4][2], bf[4][2];
#pragma unroll
    for (int m = 0; m < 4; ++m) {
      int row = wm * 64 + m * 16 + (lane & 15);
#pragma unroll
      for (int kh = 0; kh < 2; ++kh) af[m][kh] = ld_frag(la, row, kh, lane);
    }
#pragma unroll
    for (int n = 0; n < 4; ++n) {
      int row = wn * 64 + n * 16 + (lane & 15);
#pragma unroll
      for (int kh = 0; kh < 2; ++kh) bf[n][kh] = ld_frag(lb, row, kh, lane);
    }
#pragma unroll
    for (int m = 0; m < 4; ++m)
#pragma unroll
      for (int n = 0; n < 4; ++n)
#pragma unroll
        for (int kh = 0; kh < 2; ++kh)
          acc[m][n] = __builtin_amdgcn_mfma_f32_16x16x32_bf16(af[m][kh], bf[n][kh], acc[m][n], 0, 0, 0);
    if (t + 1 < NT) commit(cur ^ 1);
    __syncthreads();
    cur ^= 1;
  }

  // epilogue: C/D layout col=lane&15, row=(lane>>4)*4+reg  [m91-verified]
#pragma unroll
  for (int m = 0; m < 4; ++m) {
    int gRow0 = rowA0 + wm * 64 + m * 16 + ((lane >> 4) << 2);
#pragma unroll
    for (int n = 0; n < 4; ++n) {
      int gCol = rowB0 + wn * 64 + n * 16 + (lane & 15);
      float bv = bias[gCol];
      if (MODE == 0) {
        int sec = gCol >> 10, e = gCol & 1023;
        int h = e >> 6, d = e & 63;
        int b = gRow0 >> 11, s0 = gRow0 & 2047;
        int bh = b * 16 + h;
        if (sec == 2) {
          union { u16 u[4]; uint64_t q; } pk;
#pragma unroll
          for (int r = 0; r < 4; ++r) pk.u[r] = f2bf(acc[m][n][r] + bv);
          *(uint64_t*)&out2[((size_t)bh * 64 + d) * 2048 + s0] = pk.q;
        } else if (sec == 0) {
          // Q pre-scaled so attn can use exp2 directly
#pragma unroll
          for (int r = 0; r < 4; ++r)
            ((u16*)out0)[((size_t)bh * 2048 + (s0 + r)) * 64 + d] =
                f2bf((acc[m][n][r] + bv) * QSCALE);
        } else {
#pragma unroll
          for (int r = 0; r < 4; ++r)
            out1[((size_t)bh * 2048 + (s0 + r)) * 64 + d] = f2bf(acc[m][n][r] + bv);
        }
      } else {
        float* O = (float*)out0;
#pragma unroll
        for (int r = 0; r < 4; ++r)
          O[(size_t)(gRow0 + r) * 1024 + gCol] = acc[m][n][r] + bv;
      }
    }
  }
}

// ---------------------------------------------------------------------------
// Flash attention, causal, SWAPPED QK^T: sc = mfma(K, Q) so each lane holds
// 16 scores of ONE q-row (q = lane&15, k = n*16 + (lane>>4)*4 + r).
// Row softmax: in-lane reduce + shfl_xor(16,32). P packed 4xbf16 -> ds_write_b64.
// Block=(qt,bh) with balanced qt interleave; 4 waves x 16 q-rows; 4 blocks/CU.
// ---------------------------------------------------------------------------
__global__ __launch_bounds__(256, 4) void attn_kernel(
    const u16* __restrict__ Q, const u16* __restrict__ Kt,
    const u16* __restrict__ VT, u16* __restrict__ attn) {
  __shared__ __align__(16) u16 lsK[2][64 * 64];
  __shared__ __align__(16) u16 lsV[2][64 * 64];
  __shared__ __align__(16) u16 lsP[64 * 64];
  const int tid = threadIdx.x, lane = tid & 63, wid = tid >> 6;
  const int idx = blockIdx.x;
  // balanced interleave: every aligned 4-block group sums to const work
  const int jj = idx & 31, a = jj >> 2, bsel = jj & 3;
  const int qt = (bsel == 0) ? 31 - a : (bsel == 1) ? a : (bsel == 2) ? 15 - a : 16 + a;
  const int bh = idx >> 5;
  const int b = bh >> 4, h = bh & 15;
  const u16* Qb = Q + (size_t)bh * 2048 * 64;
  const u16* Kb = Kt + (size_t)bh * 2048 * 64;
  const u16* Vb = VT + (size_t)bh * 64 * 2048;
  const int qRow0 = qt * 64 + wid * 16;
  const int g = lane >> 4;            // k row-group selector
  const int qloc = lane & 15;         // this lane's q-row (swapped layout)

  bf16x8 qf[2];
#pragma unroll
  for (int kh = 0; kh < 2; ++kh) {
    int row = qRow0 + qloc;
    int d0 = kh * 32 + (g << 3);
    qf[kh] = *(const bf16x8*)(Qb + (size_t)row * 64 + d0);
  }

  float rowmax = -1e30f, rowsum = 0.f;   // per-lane scalars (q = qloc)
  f32x4 acc_o[4] = {};

  auto stageKV = [&](int buf, int kt) {
#pragma unroll
    for (int i = 0; i < 2; ++i) {
      int u = i * 256 + tid, r = u >> 3, s = u & 7;
      int gk = ((s ^ (r & 7)) << 3);
      gload_lds16(Kb + (size_t)(kt * 64 + r) * 64 + gk,
                  &lsK[buf][(i * 256 + wid * 64) << 3]);
    }
#pragma unroll
    for (int i = 0; i < 2; ++i) {
      int u = i * 256 + tid, r = u >> 3, s = u & 7;
      int gk = kt * 64 + ((s ^ (r & 7)) << 3);
      gload_lds16(Vb + (size_t)r * 2048 + gk,
                  &lsV[buf][(i * 256 + wid * 64) << 3]);
    }
  };

  u16* lsPw = lsP + wid * 1024;   // wave-private 16 rows x 64 cols

  const int NT = qt + 1;
  stageKV(0, 0);
  asm volatile("s_waitcnt vmcnt(0)" ::: "memory");
  __syncthreads();
  int cur = 0;
  for (int kt = 0; kt < NT; ++kt) {
    if (kt + 1 < NT) stageKV(cur ^ 1, kt + 1);

    f32x4 sc[4] = {};
    bf16x8 kf[4][2];
#pragma unroll
    for (int n = 0; n < 4; ++n) {
      int row = n * 16 + qloc;
#pragma unroll
      for (int kh = 0; kh < 2; ++kh) kf[n][kh] = ld_frag(lsK[cur], row, kh, lane);
    }
    // swapped: D[k][q] -> lane holds k = n*16 + g*4 + r for q = qRow0+qloc
#pragma unroll
    for (int n = 0; n < 4; ++n)
#pragma unroll
      for (int kh = 0; kh < 2; ++kh)
        sc[n] = __builtin_amdgcn_mfma_f32_16x16x32_bf16(kf[n][kh], qf[kh], sc[n], 0, 0, 0);

    if (kt == qt) {  // diagonal tile mask (scores pre-scaled; -1e30 -> p=0)
      int qrow = qRow0 + qloc;
#pragma unroll
      for (int n = 0; n < 4; ++n)
#pragma unroll
        for (int r = 0; r < 4; ++r) {
          int kcol = kt * 64 + n * 16 + (g << 2) + r;
          if (kcol > qrow) sc[n][r] = -1e30f;
        }
    }

    // row max: 16 in-lane + 2 cross-lane hops
    float tmax = sc[0][0];
#pragma unroll
    for (int n = 0; n < 4; ++n)
#pragma unroll
      for (int r = 0; r < 4; ++r) tmax = fmaxf(tmax, sc[n][r]);
    tmax = fmaxf(tmax, __shfl_xor(tmax, 16));
    tmax = fmaxf(tmax, __shfl_xor(tmax, 32));

    float mnew = fmaxf(rowmax, tmax);
    float rs = exp2f(rowmax - mnew);
    rowmax = mnew;

    float psum = 0.f;
#pragma unroll
    for (int n = 0; n < 4; ++n) {
      union { u16 u[4]; uint64_t q; } pk;
#pragma unroll
      for (int r = 0; r < 4; ++r) {
        float p = exp2f(sc[n][r] - mnew);
        psum += p;
        pk.u[r] = f2bf(p);
      }
      // packed P store: row=qloc, 16B-slot (2n + g>>1) ^ (row&7), half (g&1)
      int sl = ((n << 1) | (g >> 1)) ^ (qloc & 7);
      *(uint64_t*)&lsPw[qloc * 64 + (sl << 3) + ((g & 1) << 2)] = pk.q;
    }
    psum += __shfl_xor(psum, 16);
    psum += __shfl_xor(psum, 32);
    rowsum = rowsum * rs + psum;

    // redistribute rescale to acc_o row layout (q' = g*4+r)
    float rsq[4];
#pragma unroll
    for (int r = 0; r < 4; ++r) rsq[r] = __shfl(rs, (g << 2) + r);
#pragma unroll
    for (int n = 0; n < 4; ++n)
#pragma unroll
      for (int r = 0; r < 4; ++r) acc_o[n][r] *= rsq[r];

    bf16x8 pf[2], vf[4][2];
#pragma unroll
    for (int n = 0; n < 4; ++n) {
      int row = n * 16 + qloc;
#pragma unroll
      for (int kh = 0; kh < 2; ++kh) vf[n][kh] = ld_frag(lsV[cur], row, kh, lane);
    }
#pragma unroll
    for (int kh = 0; kh < 2; ++kh)
      pf[kh] = ld_frag(lsPw, qloc, kh, lane);
#pragma unroll
    for (int n = 0; n < 4; ++n)
#pragma unroll
      for (int kh = 0; kh < 2; ++kh)
        acc_o[n] = __builtin_amdgcn_mfma_f32_16x16x32_bf16(pf[kh], vf[n][kh], acc_o[n], 0, 0, 0);

    __syncthreads();
    cur ^= 1;
  }

  float inv = 1.0f / rowsum;
  float invq[4];
#pragma unroll
  for (int r = 0; r < 4; ++r) invq[r] = __shfl(inv, (g << 2) + r);
#pragma unroll
  for (int r = 0; r < 4; ++r) {
    int srow = qRow0 + (g << 2) + r;
#pragma unroll
    for (int n = 0; n < 4; ++n) {
      int d = n * 16 + qloc;
      attn[((size_t)(b * 2048 + srow)) * 1024 + h * 64 + d] = f2bf(acc_o[n][r] * invq[r]);
    }
  }
}

extern "C" void kernel_launch(void* const* d_in, const int* in_sizes, int n_in,
                              void* d_out, int out_size, void* d_ws, size_t ws_size,
                              hipStream_t stream) {
  const float* x     = (const float*)d_in[0];
  const float* w_in  = (const float*)d_in[1];
  const float* b_in  = (const float*)d_in[2];
  const float* w_out = (const float*)d_in[3];
  const float* b_out = (const float*)d_in[4];
  float* out = (float*)d_out;
  u16* ws = (u16*)d_ws;

  const size_t PH = (size_t)32 * 2048 * 64;      // 4,194,304 elems
  const size_t NW_IN = (size_t)3072 * 1024;      // 3,145,728
  const size_t NW_OUT = (size_t)1024 * 1024;     // 1,048,576
  const size_t need_big = (4 * PH + NW_IN + NW_OUT) * sizeof(u16);  // ~41.8MB

  u16* Qw  = ws;
  u16* Kw  = ws + PH;
  u16* VTw = ws + 2 * PH;
  u16* Aw  = ws + 3 * PH;   // also holds xbf during GEMM1 (sequentially safe)

  if (ws_size >= need_big) {
    u16* xbf = Aw;
    u16* wibf = ws + 4 * PH;
    u16* wobf = wibf + NW_IN;
    cvt_all<<<dim3(4096), 256, 0, stream>>>(x, w_in, w_out, xbf, wibf, wobf,
                                            (int)(PH / 8), (int)(NW_IN / 8), (int)(NW_OUT / 8));
    gemm_bt<0, false, false><<<dim3(768), 256, 0, stream>>>(xbf, wibf, b_in, Qw, Kw, VTw, 1024, 24);
    attn_kernel<<<dim3(1024), 256, 0, stream>>>(Qw, Kw, VTw, Aw);
    gemm_bt<1, false, false><<<dim3(256), 256, 0, stream>>>(Aw, wobf, b_out, out, nullptr, nullptr, 1024, 8);
  } else {
    if (ws_size < 4 * PH * sizeof(u16)) return;
    gemm_bt<0, true, true><<<dim3(768), 256, 0, stream>>>(x, w_in, b_in, Qw, Kw, VTw, 1024, 24);
    attn_kernel<<<dim3(1024), 256, 0, stream>>>(Qw, Kw, VTw, Aw);
    gemm_bt<1, false, true><<<dim3(256), 256, 0, stream>>>(Aw, w_out, b_out, out, nullptr, nullptr, 1024, 8);
  }
}

// Round 10
// 196.111 us; speedup vs baseline: 1.1156x; 1.1156x over previous
//
#include <hip/hip_runtime.h>
#include <hip/hip_bf16.h>
#include <stdint.h>

// B=2, S=2048, E=1024, H=16, DK=64, causal. Device buffers f32; internal bf16.

typedef __attribute__((ext_vector_type(4))) float f32x4;
typedef __attribute__((ext_vector_type(8))) __bf16 bf16x8;
typedef unsigned short u16;

#define QSCALE 0.18033688011112042f  // 0.125 * log2(e): folded into Q at GEMM1

__device__ __forceinline__ u16 f2bf(float f) {
  __bf16 h = (__bf16)f;
  union { __bf16 b; u16 u; } c; c.b = h; return c.u;
}

__device__ __forceinline__ void gload_lds16(const u16* g, u16* l) {
  __builtin_amdgcn_global_load_lds((const __attribute__((address_space(1))) void*)g,
                                   (__attribute__((address_space(3))) void*)l, 16, 0, 0);
}

// Fragment read from [rows][64]-bf16 LDS tile, 16B-slot XOR swizzle slot^=(row&7).
__device__ __forceinline__ bf16x8 ld_frag(const u16* ls, int row, int kh, int lane) {
  int sl = ((kh << 2) | (lane >> 4)) ^ (row & 7);
  return *(const bf16x8*)(ls + row * 64 + sl * 8);
}

__device__ __forceinline__ bf16x8 cvt8(f32x4 a, f32x4 b) {
  union { u16 u[8]; bf16x8 v; } o;
#pragma unroll
  for (int j = 0; j < 4; ++j) { o.u[j] = f2bf(a[j]); o.u[4 + j] = f2bf(b[j]); }
  return o.v;
}

// fused f32->bf16 for x, w_in, w_out (8 elems/thread, one launch)
__global__ __launch_bounds__(256) void cvt_all(
    const float* __restrict__ x, const float* __restrict__ wi,
    const float* __restrict__ wo,
    u16* __restrict__ xb, u16* __restrict__ wib, u16* __restrict__ wob,
    int n1, int n2, int n3) {
  int i = blockIdx.x * 256 + threadIdx.x;
  const float* src; u16* dst; int off;
  if (i < n1) { src = x; dst = xb; off = i; }
  else if (i < n1 + n2) { src = wi; dst = wib; off = i - n1; }
  else if (i < n1 + n2 + n3) { src = wo; dst = wob; off = i - n1 - n2; }
  else return;
  const f32x4* p = (const f32x4*)(src + (size_t)off * 8);
  *(bf16x8*)(dst + (size_t)off * 8) = cvt8(p[0], p[1]);
}

// ---------------------------------------------------------------------------
// GEMM-BT: C[M][N] = A[M][K] * Bw[N][K]^T + bias[N]; 128x128 tile, BK=64,
// 4 waves (2x2), dbuf LDS. bf16 ops: global_load_lds w16 (pre-swizzled src).
// f32 ops: reg-stage issue-early/write-late. XCD-remapped 1D grid.
// MODE 0: N=3072 QKV -> Q[bh][s][64] (PRE-SCALED by QSCALE), K[bh][s][64],
//         VT[bh][64][s] (bf16).   MODE 1: N=1024 out-proj -> f32 [M][1024]
// ---------------------------------------------------------------------------
template <int MODE, bool AF32, bool BF32>
__global__ __launch_bounds__(256, 2) void gemm_bt(
    const void* Ap, const void* Bp, const float* __restrict__ bias,
    void* out0, u16* __restrict__ out1, u16* __restrict__ out2, int K, int nbn) {
  __shared__ __align__(16) u16 lsA[2][128 * 64];
  __shared__ __align__(16) u16 lsB[2][128 * 64];
  const float* Af = (const float*)Ap; const u16* Ab = (const u16*)Ap;
  const float* Bf = (const float*)Bp; const u16* Bb = (const u16*)Bp;
  const int tid = threadIdx.x, lane = tid & 63, wid = tid >> 6;
  const int cpx = gridDim.x >> 3;
  const int wg = (blockIdx.x & 7) * cpx + (blockIdx.x >> 3);
  const int bm = wg / nbn, bn = wg % nbn;
  const int rowA0 = bm * 128, rowB0 = bn * 128;
  const int wm = wid >> 1, wn = wid & 1;

  f32x4 ra[4][2], rb[4][2];

  auto issue = [&](int buf, int k0) {
    if constexpr (AF32) {
#pragma unroll
      for (int i = 0; i < 4; ++i) {
        int u = i * 256 + tid, r = u >> 3, s = u & 7;
        const float* p = Af + (size_t)(rowA0 + r) * K + k0 + s * 8;
        ra[i][0] = *(const f32x4*)p; ra[i][1] = *(const f32x4*)(p + 4);
      }
    } else {
#pragma unroll
      for (int i = 0; i < 4; ++i) {
        int u = i * 256 + tid, r = u >> 3, s = u & 7;
        int gk = k0 + ((s ^ (r & 7)) << 3);
        gload_lds16(Ab + (size_t)(rowA0 + r) * K + gk,
                    &lsA[buf][(i * 256 + wid * 64) << 3]);
      }
    }
    if constexpr (BF32) {
#pragma unroll
      for (int i = 0; i < 4; ++i) {
        int u = i * 256 + tid, r = u >> 3, s = u & 7;
        const float* p = Bf + (size_t)(rowB0 + r) * K + k0 + s * 8;
        rb[i][0] = *(const f32x4*)p; rb[i][1] = *(const f32x4*)(p + 4);
      }
    } else {
#pragma unroll
      for (int i = 0; i < 4; ++i) {
        int u = i * 256 + tid, r = u >> 3, s = u & 7;
        int gk = k0 + ((s ^ (r & 7)) << 3);
        gload_lds16(Bb + (size_t)(rowB0 + r) * K + gk,
                    &lsB[buf][(i * 256 + wid * 64) << 3]);
      }
    }
  };
  auto commit = [&](int buf) {
    if constexpr (AF32) {
#pragma unroll
      for (int i = 0; i < 4; ++i) {
        int u = i * 256 + tid, r = u >> 3, s = u & 7;
        *(bf16x8*)&lsA[buf][r * 64 + ((s ^ (r & 7)) << 3)] = cvt8(ra[i][0], ra[i][1]);
      }
    }
    if constexpr (BF32) {
#pragma unroll
      for (int i = 0; i < 4; ++i) {
        int u = i * 256 + tid, r = u >> 3, s = u & 7;
        *(bf16x8*)&lsB[buf][r * 64 + ((s ^ (r & 7)) << 3)] = cvt8(rb[i][0], rb[i][1]);
      }
    }
  };

  f32x4 acc[4][4] = {};
  const int NT = K >> 6;
  issue(0, 0);
  commit(0);
  asm volatile("s_waitcnt vmcnt(0)" ::: "memory");
  __syncthreads();
  int cur = 0;
  for (int t = 0; t < NT; ++t) {
    if (t + 1 < NT) issue(cur ^ 1, (t + 1) << 6);
    const u16* la = lsA[cur];
    const u16* lb = lsB[cur];
    bf16x8 af[4][2], bf[4][2];
#pragma unroll
    for (int m = 0; m < 4; ++m) {
      int row = wm * 64 + m * 16 + (lane & 15);
#pragma unroll
      for (int kh = 0; kh < 2; ++kh) af[m][kh] = ld_frag(la, row, kh, lane);
    }
#pragma unroll
    for (int n = 0; n < 4; ++n) {
      int row = wn * 64 + n * 16 + (lane & 15);
#pragma unroll
      for (int kh = 0; kh < 2; ++kh) bf[n][kh] = ld_frag(lb, row, kh, lane);
    }
#pragma unroll
    for (int m = 0; m < 4; ++m)
#pragma unroll
      for (int n = 0; n < 4; ++n)
#pragma unroll
        for (int kh = 0; kh < 2; ++kh)
          acc[m][n] = __builtin_amdgcn_mfma_f32_16x16x32_bf16(af[m][kh], bf[n][kh], acc[m][n], 0, 0, 0);
    if (t + 1 < NT) commit(cur ^ 1);
    __syncthreads();
    cur ^= 1;
  }

  // epilogue: C/D layout col=lane&15, row=(lane>>4)*4+reg  [m91-verified]
#pragma unroll
  for (int m = 0; m < 4; ++m) {
    int gRow0 = rowA0 + wm * 64 + m * 16 + ((lane >> 4) << 2);
#pragma unroll
    for (int n = 0; n < 4; ++n) {
      int gCol = rowB0 + wn * 64 + n * 16 + (lane & 15);
      float bv = bias[gCol];
      if (MODE == 0) {
        int sec = gCol >> 10, e = gCol & 1023;
        int h = e >> 6, d = e & 63;
        int b = gRow0 >> 11, s0 = gRow0 & 2047;
        int bh = b * 16 + h;
        if (sec == 2) {
          union { u16 u[4]; uint64_t q; } pk;
#pragma unroll
          for (int r = 0; r < 4; ++r) pk.u[r] = f2bf(acc[m][n][r] + bv);
          *(uint64_t*)&out2[((size_t)bh * 64 + d) * 2048 + s0] = pk.q;
        } else if (sec == 0) {
          // Q pre-scaled so attn can use exp2 directly
#pragma unroll
          for (int r = 0; r < 4; ++r)
            ((u16*)out0)[((size_t)bh * 2048 + (s0 + r)) * 64 + d] =
                f2bf((acc[m][n][r] + bv) * QSCALE);
        } else {
#pragma unroll
          for (int r = 0; r < 4; ++r)
            out1[((size_t)bh * 2048 + (s0 + r)) * 64 + d] = f2bf(acc[m][n][r] + bv);
        }
      } else {
        float* O = (float*)out0;
#pragma unroll
        for (int r = 0; r < 4; ++r)
          O[(size_t)(gRow0 + r) * 1024 + gCol] = acc[m][n][r] + bv;
      }
    }
  }
}

// ---------------------------------------------------------------------------
// Flash attention, causal, SWAPPED QK^T: sc = mfma(K, Q) so each lane holds
// 16 scores of ONE q-row (q = lane&15, k = n*16 + (lane>>4)*4 + r).
// Row softmax: in-lane reduce + shfl_xor(16,32). P packed 4xbf16 -> ds_write_b64.
// bh = idx&31 (fastest) keeps XCD KV locality (XCD = idx%8 = bh%8: 4 heads
// x 512KB = 2MB per-XCD L2-resident). qt balanced on idx>>5 only: each CU's
// 4 resident blocks (idx = c mod 256) get qt summing to 62.
// ---------------------------------------------------------------------------
__global__ __launch_bounds__(256, 4) void attn_kernel(
    const u16* __restrict__ Q, const u16* __restrict__ Kt,
    const u16* __restrict__ VT, u16* __restrict__ attn) {
  __shared__ __align__(16) u16 lsK[2][64 * 64];
  __shared__ __align__(16) u16 lsV[2][64 * 64];
  __shared__ __align__(16) u16 lsP[64 * 64];
  const int tid = threadIdx.x, lane = tid & 63, wid = tid >> 6;
  const int idx = blockIdx.x;
  const int p32 = idx >> 5, a = p32 & 7, bq = p32 >> 3;
  const int qt = (bq == 0) ? a : (bq == 1) ? 15 - a : (bq == 2) ? 16 + a : 31 - a;
  const int bh = idx & 31;
  const int b = bh >> 4, h = bh & 15;
  const u16* Qb = Q + (size_t)bh * 2048 * 64;
  const u16* Kb = Kt + (size_t)bh * 2048 * 64;
  const u16* Vb = VT + (size_t)bh * 64 * 2048;
  const int qRow0 = qt * 64 + wid * 16;
  const int g = lane >> 4;            // k row-group selector
  const int qloc = lane & 15;         // this lane's q-row (swapped layout)

  bf16x8 qf[2];
#pragma unroll
  for (int kh = 0; kh < 2; ++kh) {
    int row = qRow0 + qloc;
    int d0 = kh * 32 + (g << 3);
    qf[kh] = *(const bf16x8*)(Qb + (size_t)row * 64 + d0);
  }

  float rowmax = -1e30f, rowsum = 0.f;   // per-lane scalars (q = qloc)
  f32x4 acc_o[4] = {};

  auto stageKV = [&](int buf, int kt) {
#pragma unroll
    for (int i = 0; i < 2; ++i) {
      int u = i * 256 + tid, r = u >> 3, s = u & 7;
      int gk = ((s ^ (r & 7)) << 3);
      gload_lds16(Kb + (size_t)(kt * 64 + r) * 64 + gk,
                  &lsK[buf][(i * 256 + wid * 64) << 3]);
    }
#pragma unroll
    for (int i = 0; i < 2; ++i) {
      int u = i * 256 + tid, r = u >> 3, s = u & 7;
      int gk = kt * 64 + ((s ^ (r & 7)) << 3);
      gload_lds16(Vb + (size_t)r * 2048 + gk,
                  &lsV[buf][(i * 256 + wid * 64) << 3]);
    }
  };

  u16* lsPw = lsP + wid * 1024;   // wave-private 16 rows x 64 cols

  const int NT = qt + 1;
  stageKV(0, 0);
  asm volatile("s_waitcnt vmcnt(0)" ::: "memory");
  __syncthreads();
  int cur = 0;
  for (int kt = 0; kt < NT; ++kt) {
    if (kt + 1 < NT) stageKV(cur ^ 1, kt + 1);

    f32x4 sc[4] = {};
    bf16x8 kf[4][2];
#pragma unroll
    for (int n = 0; n < 4; ++n) {
      int row = n * 16 + qloc;
#pragma unroll
      for (int kh = 0; kh < 2; ++kh) kf[n][kh] = ld_frag(lsK[cur], row, kh, lane);
    }
    // swapped: D[k][q] -> lane holds k = n*16 + g*4 + r for q = qRow0+qloc
#pragma unroll
    for (int n = 0; n < 4; ++n)
#pragma unroll
      for (int kh = 0; kh < 2; ++kh)
        sc[n] = __builtin_amdgcn_mfma_f32_16x16x32_bf16(kf[n][kh], qf[kh], sc[n], 0, 0, 0);

    if (kt == qt) {  // diagonal tile mask (scores pre-scaled; -1e30 -> p=0)
      int qrow = qRow0 + qloc;
#pragma unroll
      for (int n = 0; n < 4; ++n)
#pragma unroll
        for (int r = 0; r < 4; ++r) {
          int kcol = kt * 64 + n * 16 + (g << 2) + r;
          if (kcol > qrow) sc[n][r] = -1e30f;
        }
    }

    // row max: 16 in-lane + 2 cross-lane hops
    float tmax = sc[0][0];
#pragma unroll
    for (int n = 0; n < 4; ++n)
#pragma unroll
      for (int r = 0; r < 4; ++r) tmax = fmaxf(tmax, sc[n][r]);
    tmax = fmaxf(tmax, __shfl_xor(tmax, 16));
    tmax = fmaxf(tmax, __shfl_xor(tmax, 32));

    float mnew = fmaxf(rowmax, tmax);
    float rs = exp2f(rowmax - mnew);
    rowmax = mnew;

    float psum = 0.f;
#pragma unroll
    for (int n = 0; n < 4; ++n) {
      union { u16 u[4]; uint64_t q; } pk;
#pragma unroll
      for (int r = 0; r < 4; ++r) {
        float p = exp2f(sc[n][r] - mnew);
        psum += p;
        pk.u[r] = f2bf(p);
      }
      // packed P store: row=qloc, 16B-slot (2n + g>>1) ^ (row&7), half (g&1)
      int sl = ((n << 1) | (g >> 1)) ^ (qloc & 7);
      *(uint64_t*)&lsPw[qloc * 64 + (sl << 3) + ((g & 1) << 2)] = pk.q;
    }
    psum += __shfl_xor(psum, 16);
    psum += __shfl_xor(psum, 32);
    rowsum = rowsum * rs + psum;

    // redistribute rescale to acc_o row layout (q' = g*4+r)
    float rsq[4];
#pragma unroll
    for (int r = 0; r < 4; ++r) rsq[r] = __shfl(rs, (g << 2) + r);
#pragma unroll
    for (int n = 0; n < 4; ++n)
#pragma unroll
      for (int r = 0; r < 4; ++r) acc_o[n][r] *= rsq[r];

    bf16x8 pf[2], vf[4][2];
#pragma unroll
    for (int n = 0; n < 4; ++n) {
      int row = n * 16 + qloc;
#pragma unroll
      for (int kh = 0; kh < 2; ++kh) vf[n][kh] = ld_frag(lsV[cur], row, kh, lane);
    }
#pragma unroll
    for (int kh = 0; kh < 2; ++kh)
      pf[kh] = ld_frag(lsPw, qloc, kh, lane);
#pragma unroll
    for (int n = 0; n < 4; ++n)
#pragma unroll
      for (int kh = 0; kh < 2; ++kh)
        acc_o[n] = __builtin_amdgcn_mfma_f32_16x16x32_bf16(pf[kh], vf[n][kh], acc_o[n], 0, 0, 0);

    __syncthreads();
    cur ^= 1;
  }

  float inv = 1.0f / rowsum;
  float invq[4];
#pragma unroll
  for (int r = 0; r < 4; ++r) invq[r] = __shfl(inv, (g << 2) + r);
#pragma unroll
  for (int r = 0; r < 4; ++r) {
    int srow = qRow0 + (g << 2) + r;
#pragma unroll
    for (int n = 0; n < 4; ++n) {
      int d = n * 16 + qloc;
      attn[((size_t)(b * 2048 + srow)) * 1024 + h * 64 + d] = f2bf(acc_o[n][r] * invq[r]);
    }
  }
}

extern "C" void kernel_launch(void* const* d_in, const int* in_sizes, int n_in,
                              void* d_out, int out_size, void* d_ws, size_t ws_size,
                              hipStream_t stream) {
  const float* x     = (const float*)d_in[0];
  const float* w_in  = (const float*)d_in[1];
  const float* b_in  = (const float*)d_in[2];
  const float* w_out = (const float*)d_in[3];
  const float* b_out = (const float*)d_in[4];
  float* out = (float*)d_out;
  u16* ws = (u16*)d_ws;

  const size_t PH = (size_t)32 * 2048 * 64;      // 4,194,304 elems
  const size_t NW_IN = (size_t)3072 * 1024;      // 3,145,728
  const size_t NW_OUT = (size_t)1024 * 1024;     // 1,048,576
  const size_t need_big = (4 * PH + NW_IN + NW_OUT) * sizeof(u16);  // ~41.8MB

  u16* Qw  = ws;
  u16* Kw  = ws + PH;
  u16* VTw = ws + 2 * PH;
  u16* Aw  = ws + 3 * PH;   // also holds xbf during GEMM1 (sequentially safe)

  if (ws_size >= need_big) {
    u16* xbf = Aw;
    u16* wibf = ws + 4 * PH;
    u16* wobf = wibf + NW_IN;
    cvt_all<<<dim3(4096), 256, 0, stream>>>(x, w_in, w_out, xbf, wibf, wobf,
                                            (int)(PH / 8), (int)(NW_IN / 8), (int)(NW_OUT / 8));
    gemm_bt<0, false, false><<<dim3(768), 256, 0, stream>>>(xbf, wibf, b_in, Qw, Kw, VTw, 1024, 24);
    attn_kernel<<<dim3(1024), 256, 0, stream>>>(Qw, Kw, VTw, Aw);
    gemm_bt<1, false, false><<<dim3(256), 256, 0, stream>>>(Aw, wobf, b_out, out, nullptr, nullptr, 1024, 8);
  } else {
    if (ws_size < 4 * PH * sizeof(u16)) return;
    gemm_bt<0, true, true><<<dim3(768), 256, 0, stream>>>(x, w_in, b_in, Qw, Kw, VTw, 1024, 24);
    attn_kernel<<<dim3(1024), 256, 0, stream>>>(Qw, Kw, VTw, Aw);
    gemm_bt<1, false, true><<<dim3(256), 256, 0, stream>>>(Aw, w_out, b_out, out, nullptr, nullptr, 1024, 8);
  }
}

// Round 12
// 192.938 us; speedup vs baseline: 1.1340x; 1.0164x over previous
//
#include <hip/hip_runtime.h>
#include <hip/hip_bf16.h>
#include <stdint.h>

// B=2, S=2048, E=1024, H=16, DK=64, causal. Device buffers f32; internal bf16.

typedef __attribute__((ext_vector_type(4))) float f32x4;
typedef __attribute__((ext_vector_type(8))) __bf16 bf16x8;
typedef unsigned short u16;

#define QSCALE 0.18033688011112042f  // 0.125 * log2(e): folded into Q at GEMM1

__device__ __forceinline__ u16 f2bf(float f) {
  __bf16 h = (__bf16)f;
  union { __bf16 b; u16 u; } c; c.b = h; return c.u;
}

__device__ __forceinline__ void gload_lds16(const u16* g, u16* l) {
  __builtin_amdgcn_global_load_lds((const __attribute__((address_space(1))) void*)g,
                                   (__attribute__((address_space(3))) void*)l, 16, 0, 0);
}

// Fragment read from [rows][64]-bf16 LDS tile, 16B-slot XOR swizzle slot^=(row&7).
__device__ __forceinline__ bf16x8 ld_frag(const u16* ls, int row, int kh, int lane) {
  int sl = ((kh << 2) | (lane >> 4)) ^ (row & 7);
  return *(const bf16x8*)(ls + row * 64 + sl * 8);
}

__device__ __forceinline__ bf16x8 cvt8(f32x4 a, f32x4 b) {
  union { u16 u[8]; bf16x8 v; } o;
#pragma unroll
  for (int j = 0; j < 4; ++j) { o.u[j] = f2bf(a[j]); o.u[4 + j] = f2bf(b[j]); }
  return o.v;
}

// fused f32->bf16 for x, w_in, w_out (8 elems/thread, one launch)
__global__ __launch_bounds__(256) void cvt_all(
    const float* __restrict__ x, const float* __restrict__ wi,
    const float* __restrict__ wo,
    u16* __restrict__ xb, u16* __restrict__ wib, u16* __restrict__ wob,
    int n1, int n2, int n3) {
  int i = blockIdx.x * 256 + threadIdx.x;
  const float* src; u16* dst; int off;
  if (i < n1) { src = x; dst = xb; off = i; }
  else if (i < n1 + n2) { src = wi; dst = wib; off = i - n1; }
  else if (i < n1 + n2 + n3) { src = wo; dst = wob; off = i - n1 - n2; }
  else return;
  const f32x4* p = (const f32x4*)(src + (size_t)off * 8);
  *(bf16x8*)(dst + (size_t)off * 8) = cvt8(p[0], p[1]);
}

// ---------------------------------------------------------------------------
// GEMM-BT: C[M][N] = A[M][K] * Bw[N][K]^T + bias[N]; 128x128 tile, BK=64,
// 4 waves (2x2), dbuf LDS. bf16 ops: global_load_lds w16 (pre-swizzled src).
// f32 ops: reg-stage issue-early/write-late. XCD-remapped 1D grid.
// MODE 0: N=3072 QKV -> Q[bh][s][64] (PRE-SCALED by QSCALE), K[bh][s][64],
//         VT[bh][64][s] (bf16).   MODE 1: N=1024 out-proj -> f32 [M][1024]
// ---------------------------------------------------------------------------
template <int MODE, bool AF32, bool BF32>
__global__ __launch_bounds__(256, 2) void gemm_bt(
    const void* Ap, const void* Bp, const float* __restrict__ bias,
    void* out0, u16* __restrict__ out1, u16* __restrict__ out2, int K, int nbn) {
  __shared__ __align__(16) u16 lsA[2][128 * 64];
  __shared__ __align__(16) u16 lsB[2][128 * 64];
  const float* Af = (const float*)Ap; const u16* Ab = (const u16*)Ap;
  const float* Bf = (const float*)Bp; const u16* Bb = (const u16*)Bp;
  const int tid = threadIdx.x, lane = tid & 63, wid = tid >> 6;
  const int cpx = gridDim.x >> 3;
  const int wg = (blockIdx.x & 7) * cpx + (blockIdx.x >> 3);
  const int bm = wg / nbn, bn = wg % nbn;
  const int rowA0 = bm * 128, rowB0 = bn * 128;
  const int wm = wid >> 1, wn = wid & 1;

  f32x4 ra[4][2], rb[4][2];

  auto issue = [&](int buf, int k0) {
    if constexpr (AF32) {
#pragma unroll
      for (int i = 0; i < 4; ++i) {
        int u = i * 256 + tid, r = u >> 3, s = u & 7;
        const float* p = Af + (size_t)(rowA0 + r) * K + k0 + s * 8;
        ra[i][0] = *(const f32x4*)p; ra[i][1] = *(const f32x4*)(p + 4);
      }
    } else {
#pragma unroll
      for (int i = 0; i < 4; ++i) {
        int u = i * 256 + tid, r = u >> 3, s = u & 7;
        int gk = k0 + ((s ^ (r & 7)) << 3);
        gload_lds16(Ab + (size_t)(rowA0 + r) * K + gk,
                    &lsA[buf][(i * 256 + wid * 64) << 3]);
      }
    }
    if constexpr (BF32) {
#pragma unroll
      for (int i = 0; i < 4; ++i) {
        int u = i * 256 + tid, r = u >> 3, s = u & 7;
        const float* p = Bf + (size_t)(rowB0 + r) * K + k0 + s * 8;
        rb[i][0] = *(const f32x4*)p; rb[i][1] = *(const f32x4*)(p + 4);
      }
    } else {
#pragma unroll
      for (int i = 0; i < 4; ++i) {
        int u = i * 256 + tid, r = u >> 3, s = u & 7;
        int gk = k0 + ((s ^ (r & 7)) << 3);
        gload_lds16(Bb + (size_t)(rowB0 + r) * K + gk,
                    &lsB[buf][(i * 256 + wid * 64) << 3]);
      }
    }
  };
  auto commit = [&](int buf) {
    if constexpr (AF32) {
#pragma unroll
      for (int i = 0; i < 4; ++i) {
        int u = i * 256 + tid, r = u >> 3, s = u & 7;
        *(bf16x8*)&lsA[buf][r * 64 + ((s ^ (r & 7)) << 3)] = cvt8(ra[i][0], ra[i][1]);
      }
    }
    if constexpr (BF32) {
#pragma unroll
      for (int i = 0; i < 4; ++i) {
        int u = i * 256 + tid, r = u >> 3, s = u & 7;
        *(bf16x8*)&lsB[buf][r * 64 + ((s ^ (r & 7)) << 3)] = cvt8(rb[i][0], rb[i][1]);
      }
    }
  };

  f32x4 acc[4][4] = {};
  const int NT = K >> 6;
  issue(0, 0);
  commit(0);
  asm volatile("s_waitcnt vmcnt(0)" ::: "memory");
  __syncthreads();
  int cur = 0;
  for (int t = 0; t < NT; ++t) {
    if (t + 1 < NT) issue(cur ^ 1, (t + 1) << 6);
    const u16* la = lsA[cur];
    const u16* lb = lsB[cur];
    bf16x8 af[4][2], bf[4][2];
#pragma unroll
    for (int m = 0; m < 4; ++m) {
      int row = wm * 64 + m * 16 + (lane & 15);
#pragma unroll
      for (int kh = 0; kh < 2; ++kh) af[m][kh] = ld_frag(la, row, kh, lane);
    }
#pragma unroll
    for (int n = 0; n < 4; ++n) {
      int row = wn * 64 + n * 16 + (lane & 15);
#pragma unroll
      for (int kh = 0; kh < 2; ++kh) bf[n][kh] = ld_frag(lb, row, kh, lane);
    }
#pragma unroll
    for (int m = 0; m < 4; ++m)
#pragma unroll
      for (int n = 0; n < 4; ++n)
#pragma unroll
        for (int kh = 0; kh < 2; ++kh)
          acc[m][n] = __builtin_amdgcn_mfma_f32_16x16x32_bf16(af[m][kh], bf[n][kh], acc[m][n], 0, 0, 0);
    if (t + 1 < NT) commit(cur ^ 1);
    __syncthreads();
    cur ^= 1;
  }

  // epilogue: C/D layout col=lane&15, row=(lane>>4)*4+reg  [m91-verified]
#pragma unroll
  for (int m = 0; m < 4; ++m) {
    int gRow0 = rowA0 + wm * 64 + m * 16 + ((lane >> 4) << 2);
#pragma unroll
    for (int n = 0; n < 4; ++n) {
      int gCol = rowB0 + wn * 64 + n * 16 + (lane & 15);
      float bv = bias[gCol];
      if (MODE == 0) {
        int sec = gCol >> 10, e = gCol & 1023;
        int h = e >> 6, d = e & 63;
        int b = gRow0 >> 11, s0 = gRow0 & 2047;
        int bh = b * 16 + h;
        if (sec == 2) {
          union { u16 u[4]; uint64_t q; } pk;
#pragma unroll
          for (int r = 0; r < 4; ++r) pk.u[r] = f2bf(acc[m][n][r] + bv);
          *(uint64_t*)&out2[((size_t)bh * 64 + d) * 2048 + s0] = pk.q;
        } else if (sec == 0) {
          // Q pre-scaled so attn can use exp2 directly
#pragma unroll
          for (int r = 0; r < 4; ++r)
            ((u16*)out0)[((size_t)bh * 2048 + (s0 + r)) * 64 + d] =
                f2bf((acc[m][n][r] + bv) * QSCALE);
        } else {
#pragma unroll
          for (int r = 0; r < 4; ++r)
            out1[((size_t)bh * 2048 + (s0 + r)) * 64 + d] = f2bf(acc[m][n][r] + bv);
        }
      } else {
        float* O = (float*)out0;
#pragma unroll
        for (int r = 0; r < 4; ++r)
          O[(size_t)(gRow0 + r) * 1024 + gCol] = acc[m][n][r] + bv;
      }
    }
  }
}

// ---------------------------------------------------------------------------
// Flash attention, causal, SWAPPED QK^T: sc = mfma(K, Q); lane holds 16 scores
// of ONE q-row (q = lane&15). bh = idx&31 keeps XCD KV locality; qt balanced
// on idx>>5. T13 defer-rescale (THR=8, scores in log2 domain via QSCALE),
// per-lane partial rowsum reduced once at end, s_setprio around MFMA.
// ---------------------------------------------------------------------------
__global__ __launch_bounds__(256, 4) void attn_kernel(
    const u16* __restrict__ Q, const u16* __restrict__ Kt,
    const u16* __restrict__ VT, u16* __restrict__ attn) {
  __shared__ __align__(16) u16 lsK[2][64 * 64];
  __shared__ __align__(16) u16 lsV[2][64 * 64];
  __shared__ __align__(16) u16 lsP[64 * 64];
  const int tid = threadIdx.x, lane = tid & 63, wid = tid >> 6;
  const int idx = blockIdx.x;
  const int p32 = idx >> 5, a = p32 & 7, bq = p32 >> 3;
  const int qt = (bq == 0) ? a : (bq == 1) ? 15 - a : (bq == 2) ? 16 + a : 31 - a;
  const int bh = idx & 31;
  const int b = bh >> 4, h = bh & 15;
  const u16* Qb = Q + (size_t)bh * 2048 * 64;
  const u16* Kb = Kt + (size_t)bh * 2048 * 64;
  const u16* Vb = VT + (size_t)bh * 64 * 2048;
  const int qRow0 = qt * 64 + wid * 16;
  const int g = lane >> 4;            // k row-group selector
  const int qloc = lane & 15;         // this lane's q-row (swapped layout)

  bf16x8 qf[2];
#pragma unroll
  for (int kh = 0; kh < 2; ++kh) {
    int row = qRow0 + qloc;
    int d0 = kh * 32 + (g << 3);
    qf[kh] = *(const bf16x8*)(Qb + (size_t)row * 64 + d0);
  }

  float rowmax = -1e30f, rowsum = 0.f;   // rowsum = per-lane PARTIAL (16 k-slots)
  f32x4 acc_o[4] = {};

  auto stageKV = [&](int buf, int kt) {
#pragma unroll
    for (int i = 0; i < 2; ++i) {
      int u = i * 256 + tid, r = u >> 3, s = u & 7;
      int gk = ((s ^ (r & 7)) << 3);
      gload_lds16(Kb + (size_t)(kt * 64 + r) * 64 + gk,
                  &lsK[buf][(i * 256 + wid * 64) << 3]);
    }
#pragma unroll
    for (int i = 0; i < 2; ++i) {
      int u = i * 256 + tid, r = u >> 3, s = u & 7;
      int gk = kt * 64 + ((s ^ (r & 7)) << 3);
      gload_lds16(Vb + (size_t)r * 2048 + gk,
                  &lsV[buf][(i * 256 + wid * 64) << 3]);
    }
  };

  u16* lsPw = lsP + wid * 1024;   // wave-private 16 rows x 64 cols

  const int NT = qt + 1;
  stageKV(0, 0);
  asm volatile("s_waitcnt vmcnt(0)" ::: "memory");
  __syncthreads();
  int cur = 0;
  for (int kt = 0; kt < NT; ++kt) {
    if (kt + 1 < NT) stageKV(cur ^ 1, kt + 1);

    f32x4 sc[4] = {};
    bf16x8 kf[4][2];
#pragma unroll
    for (int n = 0; n < 4; ++n) {
      int row = n * 16 + qloc;
#pragma unroll
      for (int kh = 0; kh < 2; ++kh) kf[n][kh] = ld_frag(lsK[cur], row, kh, lane);
    }
    // swapped: D[k][q] -> lane holds k = n*16 + g*4 + r for q = qRow0+qloc
    __builtin_amdgcn_s_setprio(1);
#pragma unroll
    for (int n = 0; n < 4; ++n)
#pragma unroll
      for (int kh = 0; kh < 2; ++kh)
        sc[n] = __builtin_amdgcn_mfma_f32_16x16x32_bf16(kf[n][kh], qf[kh], sc[n], 0, 0, 0);
    __builtin_amdgcn_s_setprio(0);

    if (kt == qt) {  // diagonal tile mask (scores pre-scaled; -1e30 -> p=0)
      int qrow = qRow0 + qloc;
#pragma unroll
      for (int n = 0; n < 4; ++n)
#pragma unroll
        for (int r = 0; r < 4; ++r) {
          int kcol = kt * 64 + n * 16 + (g << 2) + r;
          if (kcol > qrow) sc[n][r] = -1e30f;
        }
    }

    // row max: 16 in-lane + 2 cross-lane hops (uniform across 4 replicas)
    float tmax = sc[0][0];
#pragma unroll
    for (int n = 0; n < 4; ++n)
#pragma unroll
      for (int r = 0; r < 4; ++r) tmax = fmaxf(tmax, sc[n][r]);
    tmax = fmaxf(tmax, __shfl_xor(tmax, 16));
    tmax = fmaxf(tmax, __shfl_xor(tmax, 32));

    // T13 defer-rescale: only pay exp2+shfl+acc-mul when max grew > 8
    if (__any(tmax > rowmax + 8.f)) {
      float mnew = fmaxf(rowmax, tmax);
      float rs = exp2f(rowmax - mnew);   // ==1 for lanes whose max didn't grow
      rowmax = mnew;
      rowsum *= rs;
      float rsq[4];
#pragma unroll
      for (int r = 0; r < 4; ++r) rsq[r] = __shfl(rs, (g << 2) + r);
#pragma unroll
      for (int n = 0; n < 4; ++n)
#pragma unroll
        for (int r = 0; r < 4; ++r) acc_o[n][r] *= rsq[r];
    }

#pragma unroll
    for (int n = 0; n < 4; ++n) {
      union { u16 u[4]; uint64_t q; } pk;
#pragma unroll
      for (int r = 0; r < 4; ++r) {
        float p = exp2f(sc[n][r] - rowmax);   // bounded by 2^8 when deferred
        rowsum += p;
        pk.u[r] = f2bf(p);
      }
      // packed P store: row=qloc, 16B-slot (2n + g>>1) ^ (row&7), half (g&1)
      int sl = ((n << 1) | (g >> 1)) ^ (qloc & 7);
      *(uint64_t*)&lsPw[qloc * 64 + (sl << 3) + ((g & 1) << 2)] = pk.q;
    }

    bf16x8 pf[2], vf[4][2];
#pragma unroll
    for (int n = 0; n < 4; ++n) {
      int row = n * 16 + qloc;
#pragma unroll
      for (int kh = 0; kh < 2; ++kh) vf[n][kh] = ld_frag(lsV[cur], row, kh, lane);
    }
#pragma unroll
    for (int kh = 0; kh < 2; ++kh)
      pf[kh] = ld_frag(lsPw, qloc, kh, lane);
    __builtin_amdgcn_s_setprio(1);
#pragma unroll
    for (int n = 0; n < 4; ++n)
#pragma unroll
      for (int kh = 0; kh < 2; ++kh)
        acc_o[n] = __builtin_amdgcn_mfma_f32_16x16x32_bf16(pf[kh], vf[n][kh], acc_o[n], 0, 0, 0);
    __builtin_amdgcn_s_setprio(0);

    __syncthreads();
    cur ^= 1;
  }

  // final: reduce partial rowsum across the 4 replicas (once, not per-tile)
  rowsum += __shfl_xor(rowsum, 16);
  rowsum += __shfl_xor(rowsum, 32);
  float inv = 1.0f / rowsum;
  float invq[4];
#pragma unroll
  for (int r = 0; r < 4; ++r) invq[r] = __shfl(inv, (g << 2) + r);
#pragma unroll
  for (int r = 0; r < 4; ++r) {
    int srow = qRow0 + (g << 2) + r;
#pragma unroll
    for (int n = 0; n < 4; ++n) {
      int d = n * 16 + qloc;
      attn[((size_t)(b * 2048 + srow)) * 1024 + h * 64 + d] = f2bf(acc_o[n][r] * invq[r]);
    }
  }
}

extern "C" void kernel_launch(void* const* d_in, const int* in_sizes, int n_in,
                              void* d_out, int out_size, void* d_ws, size_t ws_size,
                              hipStream_t stream) {
  const float* x     = (const float*)d_in[0];
  const float* w_in  = (const float*)d_in[1];
  const float* b_in  = (const float*)d_in[2];
  const float* w_out = (const float*)d_in[3];
  const float* b_out = (const float*)d_in[4];
  float* out = (float*)d_out;
  u16* ws = (u16*)d_ws;

  const size_t PH = (size_t)32 * 2048 * 64;      // 4,194,304 elems
  const size_t NW_IN = (size_t)3072 * 1024;      // 3,145,728
  const size_t NW_OUT = (size_t)1024 * 1024;     // 1,048,576
  const size_t need_big = (4 * PH + NW_IN + NW_OUT) * sizeof(u16);  // ~41.8MB

  u16* Qw  = ws;
  u16* Kw  = ws + PH;
  u16* VTw = ws + 2 * PH;
  u16* Aw  = ws + 3 * PH;   // also holds xbf during GEMM1 (sequentially safe)

  if (ws_size >= need_big) {
    u16* xbf = Aw;
    u16* wibf = ws + 4 * PH;
    u16* wobf = wibf + NW_IN;
    cvt_all<<<dim3(4096), 256, 0, stream>>>(x, w_in, w_out, xbf, wibf, wobf,
                                            (int)(PH / 8), (int)(NW_IN / 8), (int)(NW_OUT / 8));
    gemm_bt<0, false, false><<<dim3(768), 256, 0, stream>>>(xbf, wibf, b_in, Qw, Kw, VTw, 1024, 24);
    attn_kernel<<<dim3(1024), 256, 0, stream>>>(Qw, Kw, VTw, Aw);
    gemm_bt<1, false, false><<<dim3(256), 256, 0, stream>>>(Aw, wobf, b_out, out, nullptr, nullptr, 1024, 8);
  } else {
    if (ws_size < 4 * PH * sizeof(u16)) return;
    gemm_bt<0, true, true><<<dim3(768), 256, 0, stream>>>(x, w_in, b_in, Qw, Kw, VTw, 1024, 24);
    attn_kernel<<<dim3(1024), 256, 0, stream>>>(Qw, Kw, VTw, Aw);
    gemm_bt<1, false, true><<<dim3(256), 256, 0, stream>>>(Aw, w_out, b_out, out, nullptr, nullptr, 1024, 8);
  }
}